// Round 1
// baseline (188.481 us; speedup 1.0000x reference)
//
#include <hip/hip_runtime.h>

#define N_NODES 100000
#define N_EDGES 3200000
#define D_FEAT  128

// ---------------------------------------------------------------------------
// Kernel 1: per-node feature row-sum (wave-per-node, 64 lanes x float2),
// also zero-initializes the r1 accumulator (ws is poisoned 0xAA, and the
// harness does NOT re-poison between replays -> must self-init every call).
// ---------------------------------------------------------------------------
__global__ void __launch_bounds__(256) rowsum_kernel(
    const float* __restrict__ feat,
    float* __restrict__ rowsum,
    float* __restrict__ r1)
{
    const int wave = (int)((blockIdx.x * blockDim.x + threadIdx.x) >> 6);
    const int lane = (int)(threadIdx.x & 63);
    if (wave >= N_NODES) return;

    // lane i reads features[wave][2i .. 2i+1]  (coalesced 512B per wave)
    const float2 v = *reinterpret_cast<const float2*>(
        feat + (size_t)wave * D_FEAT + (size_t)lane * 2);
    float s = v.x + v.y;

    // 64-lane butterfly reduce
    #pragma unroll
    for (int off = 32; off > 0; off >>= 1)
        s += __shfl_xor(s, off, 64);

    if (lane == 0) {
        rowsum[wave] = s;
        r1[wave] = 0.0f;
    }
}

// ---------------------------------------------------------------------------
// Kernel 2: edge scatter-add of scalars. 4 edges per thread (int4 loads).
// rowsum (400 KB) and r1 (400 KB) are L2-resident; atomics are device-scope.
// ---------------------------------------------------------------------------
__global__ void __launch_bounds__(256) edge_kernel(
    const int* __restrict__ edge_src,
    const int* __restrict__ edge_dst,
    const float* __restrict__ rowsum,
    float* __restrict__ r1)
{
    const int i = (int)(blockIdx.x * blockDim.x + threadIdx.x);
    const int base = i * 4;
    if (base >= N_EDGES) return;

    const int4 s4 = *reinterpret_cast<const int4*>(edge_src + base);
    const int4 d4 = *reinterpret_cast<const int4*>(edge_dst + base);

    const float v0 = rowsum[s4.x];
    const float v1 = rowsum[s4.y];
    const float v2 = rowsum[s4.z];
    const float v3 = rowsum[s4.w];

    atomicAdd(&r1[d4.x], v0);
    atomicAdd(&r1[d4.y], v1);
    atomicAdd(&r1[d4.z], v2);
    atomicAdd(&r1[d4.w], v3);
}

// ---------------------------------------------------------------------------
// Kernel 3: activation chain + truncating int cast.
// out = int32( 10 * leaky( 16 * leaky(r1, 0.1), 0.1) )
// ---------------------------------------------------------------------------
__global__ void __launch_bounds__(256) final_kernel(
    const float* __restrict__ r1,
    int* __restrict__ out)
{
    const int i = (int)(blockIdx.x * blockDim.x + threadIdx.x);
    if (i >= N_NODES) return;

    const float x  = r1[i];
    const float a1 = (x  > 0.0f) ? x  : 0.1f * x;
    const float r2 = 16.0f * a1;
    const float a2 = (r2 > 0.0f) ? r2 : 0.1f * r2;
    const float r3 = 10.0f * a2;
    out[i] = (int)r3;   // astype(int32): truncation toward zero
}

extern "C" void kernel_launch(void* const* d_in, const int* in_sizes, int n_in,
                              void* d_out, int out_size, void* d_ws, size_t ws_size,
                              hipStream_t stream)
{
    const float* feat     = (const float*)d_in[0];
    const int*   edge_src = (const int*)d_in[1];   // harness delivers integers as int32
    const int*   edge_dst = (const int*)d_in[2];
    int*         out      = (int*)d_out;

    float* rowsum = (float*)d_ws;            // N_NODES floats
    float* r1     = rowsum + N_NODES;        // N_NODES floats

    // Kernel 1: 1 wave per node -> N_NODES*64 threads
    {
        const int threads = 256;
        const int waves_per_block = threads / 64;
        const int blocks = (N_NODES + waves_per_block - 1) / waves_per_block;
        rowsum_kernel<<<blocks, threads, 0, stream>>>(feat, rowsum, r1);
    }

    // Kernel 2: 4 edges per thread
    {
        const int threads = 256;
        const int n_thr = N_EDGES / 4;
        const int blocks = (n_thr + threads - 1) / threads;
        edge_kernel<<<blocks, threads, 0, stream>>>(edge_src, edge_dst, rowsum, r1);
    }

    // Kernel 3: 1 thread per node
    {
        const int threads = 256;
        const int blocks = (N_NODES + threads - 1) / threads;
        final_kernel<<<blocks, threads, 0, stream>>>(r1, out);
    }
}